// Round 1
// baseline (199.900 us; speedup 1.0000x reference)
//
#include <hip/hip_runtime.h>
#include <math.h>

static constexpr int Bq  = 8;
static constexpr int DIN = 1024;
static constexpr int TTT = 2048;
static constexpr int KCB = 8192;

// d_out layout (floats)
static constexpr size_t OUT_OFS  = 0;
static constexpr size_t LOSS_OFS = (size_t)Bq * DIN * TTT;      // 16777216 (16 zeros)
static constexpr size_t IDX_OFS  = LOSS_OFS + 16;               // 16777232 (B*T)
static constexpr size_t ZE_OFS   = IDX_OFS + (size_t)Bq * TTT;  // 16793616 (B*8*T)

// ws layout (float offsets)
static constexpr size_t WS_CBN  = 0;          // 8192*8 normalized codebook
static constexpr size_t WS_C2   = 65536;      // 8192 ||c_n||^2
static constexpr size_t WS_WT   = 73728;      // 1024*8 transposed w_in
static constexpr size_t WS_ENC  = 81920;      // 16384*8 z_e row-major [row][cd]
static constexpr size_t WS_PART = 212992;     // float2[32][16384] partial (dist, idxbits)
static constexpr size_t WS_IDXI = WS_PART + (size_t)2 * 32 * 16384; // 16384 ints

// ---------------- K0: normalize codebook, transpose w_in, zero losses ----------
__global__ __launch_bounds__(256) void k0_prep(
    const float* __restrict__ w_in, const float* __restrict__ codebook,
    float* __restrict__ ws, float* __restrict__ out)
{
  int tid = blockIdx.x * 256 + threadIdx.x;
  if (tid < KCB) {
    const float4* cp = (const float4*)(codebook + (size_t)tid * 8);
    float4 a = cp[0], b = cp[1];
    float v[8] = {a.x, a.y, a.z, a.w, b.x, b.y, b.z, b.w};
    float n2 = 0.f;
#pragma unroll
    for (int o = 0; o < 8; o++) n2 = fmaf(v[o], v[o], n2);
    float dn = fmaxf(sqrtf(n2), 1e-12f);
    float u[8];
    float s2 = 0.f;
#pragma unroll
    for (int o = 0; o < 8; o++) { u[o] = v[o] / dn; s2 = fmaf(u[o], u[o], s2); }
    float4* wp = (float4*)(ws + WS_CBN + (size_t)tid * 8);
    wp[0] = make_float4(u[0], u[1], u[2], u[3]);
    wp[1] = make_float4(u[4], u[5], u[6], u[7]);
    ws[WS_C2 + tid] = s2;
  } else if (tid < KCB + DIN) {
    int d = tid - KCB;
#pragma unroll
    for (int o = 0; o < 8; o++) ws[WS_WT + (size_t)d * 8 + o] = w_in[(size_t)o * DIN + d];
  } else if (tid < KCB + DIN + 16) {
    out[LOSS_OFS + (tid - KCB - DIN)] = 0.f;  // commit_loss + codebook_loss zeros
  }
}

// ---------------- K1: z_e = w_in @ z + b_in  (HBM-bound, 64 MiB read) ----------
// grid 256 = B(8) x Ttiles(32), block 512. Each block: 64 t's, all 1024 d.
// tt = tid&15 -> 4 t's via float4; dg = tid>>4 -> 32-d chunk. LDS reduce 32 partials.
__global__ __launch_bounds__(512) void k1_proj_in(
    const float* __restrict__ z, const float* __restrict__ b_in,
    float* __restrict__ ws, float* __restrict__ out)
{
  __shared__ __align__(16) float lds[16384];  // 64 KB: wt staging, then partial[32][8][64]
  int tid = threadIdx.x;
  int bx = blockIdx.x;
  int b = bx >> 5;
  int t0 = (bx & 31) << 6;
  {
    const float4* src = (const float4*)(ws + WS_WT);
    float4* dst = (float4*)lds;
#pragma unroll
    for (int i = 0; i < 4; i++) dst[tid + 512 * i] = src[tid + 512 * i];
  }
  __syncthreads();
  int tt = tid & 15;
  int dg = tid >> 4;
  const float* zb = z + (size_t)b * DIN * TTT + t0 + (tt << 2);
  float4 acc[8];
#pragma unroll
  for (int o = 0; o < 8; o++) acc[o] = make_float4(0.f, 0.f, 0.f, 0.f);
  int dbase = dg << 5;
  const float4* wl = (const float4*)lds;
#pragma unroll 4
  for (int i = 0; i < 32; i++) {
    int d = dbase + i;
    float4 zv = *(const float4*)(zb + (size_t)d * TTT);
    float4 w0 = wl[d * 2 + 0];
    float4 w1 = wl[d * 2 + 1];
#define ACC1(o, wsc)                                    \
    acc[o].x = fmaf(wsc, zv.x, acc[o].x);               \
    acc[o].y = fmaf(wsc, zv.y, acc[o].y);               \
    acc[o].z = fmaf(wsc, zv.z, acc[o].z);               \
    acc[o].w = fmaf(wsc, zv.w, acc[o].w);
    ACC1(0, w0.x) ACC1(1, w0.y) ACC1(2, w0.z) ACC1(3, w0.w)
    ACC1(4, w1.x) ACC1(5, w1.y) ACC1(6, w1.z) ACC1(7, w1.w)
#undef ACC1
  }
  __syncthreads();
  {
    float4* pl = (float4*)lds;
#pragma unroll
    for (int o = 0; o < 8; o++) pl[dg * 128 + o * 16 + tt] = acc[o];
  }
  __syncthreads();
  int o = tid >> 6;
  int t = tid & 63;
  float s = 0.f;
#pragma unroll
  for (int g = 0; g < 32; g++) s += lds[g * 512 + o * 64 + t];
  s += b_in[o];
  out[ZE_OFS + ((size_t)b * 8 + o) * TTT + t0 + t] = s;
  ws[WS_ENC + ((size_t)(b * TTT + t0 + t)) * 8 + o] = s;
}

// ---------------- K2: VQ scan (VALU-bound). grid 512 = rowblocks(16) x chunks(32)
// block 256, R=4 rows/thread in regs, C=256 codes/chunk broadcast from LDS.
__global__ __launch_bounds__(256) void k2_scan(float* __restrict__ ws)
{
  __shared__ __align__(16) float scb[256 * 8];
  __shared__ float sc2[256];
  int tid = threadIdx.x;
  int rb = blockIdx.x >> 5;
  int ch = blockIdx.x & 31;
  int k0 = ch << 8;
  {
    const float4* src = (const float4*)(ws + WS_CBN + (size_t)(k0 + tid) * 8);
    float4* dst = (float4*)scb;
    dst[tid * 2] = src[0];
    dst[tid * 2 + 1] = src[1];
    sc2[tid] = ws[WS_C2 + k0 + tid];
  }
  int rbase = (rb << 10) + tid;
  float en[4][8], e2[4], best[4];
  int bidx[4];
#pragma unroll
  for (int j = 0; j < 4; j++) {
    int r = rbase + (j << 8);
    const float4* ep = (const float4*)(ws + WS_ENC + (size_t)r * 8);
    float4 a = ep[0], c = ep[1];
    float n2 = 0.f;
    n2 = fmaf(a.x, a.x, n2); n2 = fmaf(a.y, a.y, n2);
    n2 = fmaf(a.z, a.z, n2); n2 = fmaf(a.w, a.w, n2);
    n2 = fmaf(c.x, c.x, n2); n2 = fmaf(c.y, c.y, n2);
    n2 = fmaf(c.z, c.z, n2); n2 = fmaf(c.w, c.w, n2);
    float dn = fmaxf(sqrtf(n2), 1e-12f);
    en[j][0] = a.x / dn; en[j][1] = a.y / dn; en[j][2] = a.z / dn; en[j][3] = a.w / dn;
    en[j][4] = c.x / dn; en[j][5] = c.y / dn; en[j][6] = c.z / dn; en[j][7] = c.w / dn;
    float s2 = 0.f;
#pragma unroll
    for (int o = 0; o < 8; o++) s2 = fmaf(en[j][o], en[j][o], s2);
    e2[j] = s2;
    best[j] = 3.4e38f;
    bidx[j] = 0;
  }
  __syncthreads();
  const float4* cb4 = (const float4*)scb;
#pragma unroll 2
  for (int k = 0; k < 256; k++) {
    float4 c0 = cb4[k * 2];
    float4 c1 = cb4[k * 2 + 1];
    float cc = sc2[k];
#pragma unroll
    for (int j = 0; j < 4; j++) {
      float dot = 0.f;
      dot = fmaf(en[j][0], c0.x, dot); dot = fmaf(en[j][1], c0.y, dot);
      dot = fmaf(en[j][2], c0.z, dot); dot = fmaf(en[j][3], c0.w, dot);
      dot = fmaf(en[j][4], c1.x, dot); dot = fmaf(en[j][5], c1.y, dot);
      dot = fmaf(en[j][6], c1.z, dot); dot = fmaf(en[j][7], c1.w, dot);
      float dist = fmaf(-2.f, dot, e2[j]) + cc;
      if (dist < best[j]) { best[j] = dist; bidx[j] = k0 + k; }  // strict <: first min wins
    }
  }
  float2* part = (float2*)(ws + WS_PART);
#pragma unroll
  for (int j = 0; j < 4; j++) {
    int r = rbase + (j << 8);
    part[(size_t)ch * 16384 + r] = make_float2(best[j], __int_as_float(bidx[j]));
  }
}

// ---------------- K2b: reduce 32 chunk-partials per row, deterministic order ----
__global__ __launch_bounds__(256) void k2b_reduce(float* __restrict__ ws, float* __restrict__ out)
{
  int r = blockIdx.x * 256 + threadIdx.x;
  const float2* part = (const float2*)(ws + WS_PART);
  float best = 3.4e38f;
  int bi = 0;
#pragma unroll 4
  for (int ch = 0; ch < 32; ch++) {
    float2 p = part[(size_t)ch * 16384 + r];
    if (p.x < best) { best = p.x; bi = __float_as_int(p.y); }  // ascending chunk => first min
  }
  out[IDX_OFS + r] = (float)bi;
  ((int*)(ws + WS_IDXI))[r] = bi;
}

// ---------------- K3: out = w_out @ codebook[idx] + b_out (HBM write-bound) -----
// grid 1024 = b(8) x thalf(2) x dtile(64); block 256; each thread 4 t's, 16 d's.
__global__ __launch_bounds__(256) void k3_proj_out(
    const float* __restrict__ codebook, const float* __restrict__ w_out,
    const float* __restrict__ b_out, const float* __restrict__ ws,
    float* __restrict__ out)
{
  int bx = blockIdx.x;
  int b = bx >> 7;
  int th = (bx >> 6) & 1;
  int dt = bx & 63;
  int tid = threadIdx.x;
  int t = (th << 10) + (tid << 2);
  const int* idxp = (const int*)(ws + WS_IDXI);
  int4 id = *(const int4*)(idxp + b * TTT + t);
  const float4* cbp = (const float4*)codebook;
  float4 c00 = cbp[(size_t)id.x * 2], c01 = cbp[(size_t)id.x * 2 + 1];
  float4 c10 = cbp[(size_t)id.y * 2], c11 = cbp[(size_t)id.y * 2 + 1];
  float4 c20 = cbp[(size_t)id.z * 2], c21 = cbp[(size_t)id.z * 2 + 1];
  float4 c30 = cbp[(size_t)id.w * 2], c31 = cbp[(size_t)id.w * 2 + 1];
  int d0 = dt << 4;
#pragma unroll 4
  for (int dd = 0; dd < 16; dd++) {
    int d = d0 + dd;
    const float* wr = w_out + (size_t)d * 8;
    float w0 = wr[0], w1 = wr[1], w2 = wr[2], w3 = wr[3];
    float w4 = wr[4], w5 = wr[5], w6 = wr[6], w7 = wr[7];
    float bb = b_out[d];
#define DOT8(lo, hi)                                                          \
    fmaf(w7, hi.w, fmaf(w6, hi.z, fmaf(w5, hi.y, fmaf(w4, hi.x,              \
    fmaf(w3, lo.w, fmaf(w2, lo.z, fmaf(w1, lo.y, fmaf(w0, lo.x, bb))))))))
    float4 r;
    r.x = DOT8(c00, c01);
    r.y = DOT8(c10, c11);
    r.z = DOT8(c20, c21);
    r.w = DOT8(c30, c31);
#undef DOT8
    *(float4*)(out + OUT_OFS + ((size_t)b * DIN + d) * TTT + t) = r;
  }
}

extern "C" void kernel_launch(void* const* d_in, const int* in_sizes, int n_in,
                              void* d_out, int out_size, void* d_ws, size_t ws_size,
                              hipStream_t stream) {
  const float* z        = (const float*)d_in[0];
  const float* w_in     = (const float*)d_in[1];
  const float* b_in     = (const float*)d_in[2];
  const float* w_out    = (const float*)d_in[3];
  const float* b_out    = (const float*)d_in[4];
  const float* codebook = (const float*)d_in[5];
  float* out = (float*)d_out;
  float* ws  = (float*)d_ws;

  k0_prep<<<dim3(37), dim3(256), 0, stream>>>(w_in, codebook, ws, out);
  k1_proj_in<<<dim3(256), dim3(512), 0, stream>>>(z, b_in, ws, out);
  k2_scan<<<dim3(512), dim3(256), 0, stream>>>(ws);
  k2b_reduce<<<dim3(64), dim3(256), 0, stream>>>(ws, out);
  k3_proj_out<<<dim3(1024), dim3(256), 0, stream>>>(codebook, w_out, b_out, ws, out);
}

// Round 2
// 196.052 us; speedup vs baseline: 1.0196x; 1.0196x over previous
//
#include <hip/hip_runtime.h>
#include <math.h>

static constexpr int Bq  = 8;
static constexpr int DIN = 1024;
static constexpr int TTT = 2048;
static constexpr int KCB = 8192;

static constexpr int NCH = 64;    // VQ chunks
static constexpr int CPC = 128;   // codes per chunk (NCH*CPC == KCB)

// d_out layout (floats)
static constexpr size_t OUT_OFS  = 0;
static constexpr size_t LOSS_OFS = (size_t)Bq * DIN * TTT;      // 16777216 (16 zeros)
static constexpr size_t IDX_OFS  = LOSS_OFS + 16;               // 16777232 (B*T)
static constexpr size_t ZE_OFS   = IDX_OFS + (size_t)Bq * TTT;  // 16793616 (B*8*T)

// ws layout (float offsets)
static constexpr size_t WS_CBN  = 0;          // 8192*8 normalized codebook
static constexpr size_t WS_C2   = 65536;      // 8192 0.5*||c_n||^2
static constexpr size_t WS_WT   = 73728;      // 1024*8 transposed w_in
static constexpr size_t WS_ENC  = 81920;      // 16384*8 z_e row-major [row][cd]
static constexpr size_t WS_PART = 212992;     // float2[NCH][16384] partial (score, idxbits)
static constexpr size_t WS_IDXI = WS_PART + (size_t)2 * NCH * 16384; // 16384 ints

// ---------------- K0: normalize codebook, transpose w_in, zero losses ----------
__global__ __launch_bounds__(256) void k0_prep(
    const float* __restrict__ w_in, const float* __restrict__ codebook,
    float* __restrict__ ws, float* __restrict__ out)
{
  int tid = blockIdx.x * 256 + threadIdx.x;
  if (tid < KCB) {
    const float4* cp = (const float4*)(codebook + (size_t)tid * 8);
    float4 a = cp[0], b = cp[1];
    float v[8] = {a.x, a.y, a.z, a.w, b.x, b.y, b.z, b.w};
    float n2 = 0.f;
#pragma unroll
    for (int o = 0; o < 8; o++) n2 = fmaf(v[o], v[o], n2);
    float dn = fmaxf(sqrtf(n2), 1e-12f);
    float u[8];
    float s2 = 0.f;
#pragma unroll
    for (int o = 0; o < 8; o++) { u[o] = v[o] / dn; s2 = fmaf(u[o], u[o], s2); }
    float4* wp = (float4*)(ws + WS_CBN + (size_t)tid * 8);
    wp[0] = make_float4(u[0], u[1], u[2], u[3]);
    wp[1] = make_float4(u[4], u[5], u[6], u[7]);
    ws[WS_C2 + tid] = 0.5f * s2;  // folded half-norm for score = 0.5*c2 - dot
  } else if (tid < KCB + DIN) {
    int d = tid - KCB;
#pragma unroll
    for (int o = 0; o < 8; o++) ws[WS_WT + (size_t)d * 8 + o] = w_in[(size_t)o * DIN + d];
  } else if (tid < KCB + DIN + 16) {
    out[LOSS_OFS + (tid - KCB - DIN)] = 0.f;  // commit_loss + codebook_loss zeros
  }
}

// ---------------- K1: z_e = w_in @ z + b_in  (HBM-bound, 64 MiB read) ----------
__global__ __launch_bounds__(512) void k1_proj_in(
    const float* __restrict__ z, const float* __restrict__ b_in,
    float* __restrict__ ws, float* __restrict__ out)
{
  __shared__ __align__(16) float lds[16384];  // 64 KB: wt staging, then partial[32][8][64]
  int tid = threadIdx.x;
  int bx = blockIdx.x;
  int b = bx >> 5;
  int t0 = (bx & 31) << 6;
  {
    const float4* src = (const float4*)(ws + WS_WT);
    float4* dst = (float4*)lds;
#pragma unroll
    for (int i = 0; i < 4; i++) dst[tid + 512 * i] = src[tid + 512 * i];
  }
  __syncthreads();
  int tt = tid & 15;
  int dg = tid >> 4;
  const float* zb = z + (size_t)b * DIN * TTT + t0 + (tt << 2);
  float4 acc[8];
#pragma unroll
  for (int o = 0; o < 8; o++) acc[o] = make_float4(0.f, 0.f, 0.f, 0.f);
  int dbase = dg << 5;
  const float4* wl = (const float4*)lds;
#pragma unroll 8
  for (int i = 0; i < 32; i++) {
    int d = dbase + i;
    float4 zv = *(const float4*)(zb + (size_t)d * TTT);
    float4 w0 = wl[d * 2 + 0];
    float4 w1 = wl[d * 2 + 1];
#define ACC1(o, wsc)                                    \
    acc[o].x = fmaf(wsc, zv.x, acc[o].x);               \
    acc[o].y = fmaf(wsc, zv.y, acc[o].y);               \
    acc[o].z = fmaf(wsc, zv.z, acc[o].z);               \
    acc[o].w = fmaf(wsc, zv.w, acc[o].w);
    ACC1(0, w0.x) ACC1(1, w0.y) ACC1(2, w0.z) ACC1(3, w0.w)
    ACC1(4, w1.x) ACC1(5, w1.y) ACC1(6, w1.z) ACC1(7, w1.w)
#undef ACC1
  }
  __syncthreads();
  {
    float4* pl = (float4*)lds;
#pragma unroll
    for (int o = 0; o < 8; o++) pl[dg * 128 + o * 16 + tt] = acc[o];
  }
  __syncthreads();
  int o = tid >> 6;
  int t = tid & 63;
  float s = 0.f;
#pragma unroll
  for (int g = 0; g < 32; g++) s += lds[g * 512 + o * 64 + t];
  s += b_in[o];
  out[ZE_OFS + ((size_t)b * 8 + o) * TTT + t0 + t] = s;
  ws[WS_ENC + ((size_t)(b * TTT + t0 + t)) * 8 + o] = s;
}

// ---------------- K2: VQ scan. grid 512 = rowblocks(8) x chunks(64)
// block 256, R=8 rows/thread in named float4 regs (negated normalized enc),
// CPC=128 codes/chunk staged in LDS. score = 0.5*||c||^2 - enc_n.c  (monotone
// transform of reference dist per row, so argmin + tie order preserved).
__global__ __launch_bounds__(256) void k2_scan(float* __restrict__ ws)
{
  __shared__ __align__(16) float4 scb[CPC * 2];
  __shared__ float sch[CPC];
  int tid = threadIdx.x;
  int rb = blockIdx.x >> 6;  // 8 rowblocks of 2048 rows
  int ch = blockIdx.x & 63;  // 64 chunks
  int k0 = ch << 7;          // CPC codes per chunk
  if (tid < CPC) {
    const float4* src = (const float4*)(ws + WS_CBN + (size_t)(k0 + tid) * 8);
    scb[tid * 2]     = src[0];
    scb[tid * 2 + 1] = src[1];
    sch[tid] = ws[WS_C2 + k0 + tid];
  }
  int rbase = (rb << 11) + tid;  // rows rbase + j*256, j<8

#define DECL_ROW(j) float4 m##j##a, m##j##b; float b##j = 3.4e38f; int i##j = 0;
  DECL_ROW(0) DECL_ROW(1) DECL_ROW(2) DECL_ROW(3)
  DECL_ROW(4) DECL_ROW(5) DECL_ROW(6) DECL_ROW(7)
#undef DECL_ROW

#define LOAD_ROW(j) {                                                         \
    int r = rbase + (j << 8);                                                 \
    const float4* ep = (const float4*)(ws + WS_ENC + (size_t)r * 8);          \
    float4 a = ep[0], c = ep[1];                                              \
    float n2 = 0.f;                                                           \
    n2 = fmaf(a.x, a.x, n2); n2 = fmaf(a.y, a.y, n2);                         \
    n2 = fmaf(a.z, a.z, n2); n2 = fmaf(a.w, a.w, n2);                         \
    n2 = fmaf(c.x, c.x, n2); n2 = fmaf(c.y, c.y, n2);                         \
    n2 = fmaf(c.z, c.z, n2); n2 = fmaf(c.w, c.w, n2);                         \
    float dn = fmaxf(sqrtf(n2), 1e-12f);                                      \
    m##j##a.x = -(a.x / dn); m##j##a.y = -(a.y / dn);                         \
    m##j##a.z = -(a.z / dn); m##j##a.w = -(a.w / dn);                         \
    m##j##b.x = -(c.x / dn); m##j##b.y = -(c.y / dn);                         \
    m##j##b.z = -(c.z / dn); m##j##b.w = -(c.w / dn); }
  LOAD_ROW(0) LOAD_ROW(1) LOAD_ROW(2) LOAD_ROW(3)
  LOAD_ROW(4) LOAD_ROW(5) LOAD_ROW(6) LOAD_ROW(7)
#undef LOAD_ROW

  __syncthreads();
#pragma unroll 4
  for (int k = 0; k < CPC; k++) {
    float4 c0 = scb[2 * k];
    float4 c1 = scb[2 * k + 1];
    float cc = sch[k];
    int kk = k0 + k;
#define STEP(j) {                                                             \
    float s = cc;                                                             \
    s = fmaf(m##j##a.x, c0.x, s); s = fmaf(m##j##a.y, c0.y, s);               \
    s = fmaf(m##j##a.z, c0.z, s); s = fmaf(m##j##a.w, c0.w, s);               \
    s = fmaf(m##j##b.x, c1.x, s); s = fmaf(m##j##b.y, c1.y, s);               \
    s = fmaf(m##j##b.z, c1.z, s); s = fmaf(m##j##b.w, c1.w, s);               \
    if (s < b##j) { b##j = s; i##j = kk; } }
    STEP(0) STEP(1) STEP(2) STEP(3) STEP(4) STEP(5) STEP(6) STEP(7)
#undef STEP
  }
  float2* part = (float2*)(ws + WS_PART);
#define STORE_ROW(j) \
  part[(size_t)ch * 16384 + rbase + (j << 8)] = make_float2(b##j, __int_as_float(i##j));
  STORE_ROW(0) STORE_ROW(1) STORE_ROW(2) STORE_ROW(3)
  STORE_ROW(4) STORE_ROW(5) STORE_ROW(6) STORE_ROW(7)
#undef STORE_ROW
}

// ---------------- K2b: reduce NCH chunk-partials per row, deterministic order --
__global__ __launch_bounds__(256) void k2b_reduce(float* __restrict__ ws, float* __restrict__ out)
{
  int r = blockIdx.x * 256 + threadIdx.x;
  const float2* part = (const float2*)(ws + WS_PART);
  float best = 3.4e38f;
  int bi = 0;
#pragma unroll 8
  for (int ch = 0; ch < NCH; ch++) {
    float2 p = part[(size_t)ch * 16384 + r];
    if (p.x < best) { best = p.x; bi = __float_as_int(p.y); }  // ascending chunk => first min
  }
  out[IDX_OFS + r] = (float)bi;
  ((int*)(ws + WS_IDXI))[r] = bi;
}

// ---------------- K3: out = w_out @ codebook[idx] + b_out (HBM write-bound) -----
__global__ __launch_bounds__(256) void k3_proj_out(
    const float* __restrict__ codebook, const float* __restrict__ w_out,
    const float* __restrict__ b_out, const float* __restrict__ ws,
    float* __restrict__ out)
{
  int bx = blockIdx.x;
  int b = bx >> 7;
  int th = (bx >> 6) & 1;
  int dt = bx & 63;
  int tid = threadIdx.x;
  int t = (th << 10) + (tid << 2);
  const int* idxp = (const int*)(ws + WS_IDXI);
  int4 id = *(const int4*)(idxp + b * TTT + t);
  const float4* cbp = (const float4*)codebook;
  float4 c00 = cbp[(size_t)id.x * 2], c01 = cbp[(size_t)id.x * 2 + 1];
  float4 c10 = cbp[(size_t)id.y * 2], c11 = cbp[(size_t)id.y * 2 + 1];
  float4 c20 = cbp[(size_t)id.z * 2], c21 = cbp[(size_t)id.z * 2 + 1];
  float4 c30 = cbp[(size_t)id.w * 2], c31 = cbp[(size_t)id.w * 2 + 1];
  int d0 = dt << 4;
#pragma unroll 4
  for (int dd = 0; dd < 16; dd++) {
    int d = d0 + dd;
    const float* wr = w_out + (size_t)d * 8;
    float w0 = wr[0], w1 = wr[1], w2 = wr[2], w3 = wr[3];
    float w4 = wr[4], w5 = wr[5], w6 = wr[6], w7 = wr[7];
    float bb = b_out[d];
#define DOT8(lo, hi)                                                          \
    fmaf(w7, hi.w, fmaf(w6, hi.z, fmaf(w5, hi.y, fmaf(w4, hi.x,              \
    fmaf(w3, lo.w, fmaf(w2, lo.z, fmaf(w1, lo.y, fmaf(w0, lo.x, bb))))))))
    float4 r;
    r.x = DOT8(c00, c01);
    r.y = DOT8(c10, c11);
    r.z = DOT8(c20, c21);
    r.w = DOT8(c30, c31);
#undef DOT8
    *(float4*)(out + OUT_OFS + ((size_t)b * DIN + d) * TTT + t) = r;
  }
}

extern "C" void kernel_launch(void* const* d_in, const int* in_sizes, int n_in,
                              void* d_out, int out_size, void* d_ws, size_t ws_size,
                              hipStream_t stream) {
  const float* z        = (const float*)d_in[0];
  const float* w_in     = (const float*)d_in[1];
  const float* b_in     = (const float*)d_in[2];
  const float* w_out    = (const float*)d_in[3];
  const float* b_out    = (const float*)d_in[4];
  const float* codebook = (const float*)d_in[5];
  float* out = (float*)d_out;
  float* ws  = (float*)d_ws;

  k0_prep<<<dim3(37), dim3(256), 0, stream>>>(w_in, codebook, ws, out);
  k1_proj_in<<<dim3(256), dim3(512), 0, stream>>>(z, b_in, ws, out);
  k2_scan<<<dim3(512), dim3(256), 0, stream>>>(ws);
  k2b_reduce<<<dim3(64), dim3(256), 0, stream>>>(ws, out);
  k3_proj_out<<<dim3(1024), dim3(256), 0, stream>>>(codebook, w_out, b_out, ws, out);
}